// Round 8
// baseline (406.933 us; speedup 1.0000x reference)
//
#include <hip/hip_runtime.h>

#define VDIM 207
#define LDIM 128
#define VP 224            // padded V (multiple of 16, covers K-steps 7*32)
#define VL (VDIM*LDIM)    // 26496
#define NC 1024           // B*C = 32*32
#define NPOINT (32*VL)    // B*V*L = 847872
#define APITCH 232        // LDS row pitch (u16): 464 B/row
#define SWZ(row, colb) ((row) * 464 + ((colb) ^ (((row) & 1) << 5)))

typedef unsigned short u16;
typedef unsigned int u32;
typedef __attribute__((ext_vector_type(4))) float f32x4;
typedef __attribute__((ext_vector_type(8))) short s16x8;

__device__ __forceinline__ u16 f2bf(float f) {
  u32 u = __float_as_uint(f);
  return (u16)((u + 0x7FFFu + ((u >> 16) & 1u)) >> 16);  // RNE
}
__device__ __forceinline__ float bf2f(u16 h) {
  return __uint_as_float(((u32)h) << 16);
}

// ---- prep: MT[2i] = bf16(A_i^T) zero-padded 224x224; WT (f32 fallback); Wb bf16
__global__ void k_prep(const float* __restrict__ A0, const float* __restrict__ A1,
                       const float* __restrict__ A2, const float* __restrict__ W,
                       u16* __restrict__ MT, float* __restrict__ WT,
                       u16* __restrict__ Wb) {
  int idx = blockIdx.x * 256 + threadIdx.x;
  if (idx < 3 * VP * VP) {
    int i = idx / (VP * VP);
    int r = idx % (VP * VP);
    int w = r / VP, v = r % VP;
    const float* A = (i == 0) ? A0 : ((i == 1) ? A1 : A2);
    float f = (w < VDIM && v < VDIM) ? A[v * VDIM + w] : 0.f;
    MT[(size_t)(2 * i) * (VP * VP) + r] = f2bf(f);
  } else {
    int j = idx - 3 * VP * VP;
    if (j < VP * 32) {
      int k = j >> 5, o = j & 31;
      WT[j] = W[o * 224 + k];
    } else if (j < 2 * VP * 32) {
      int j2 = j - VP * 32;
      Wb[j2] = f2bf(W[j2]);
    }
  }
}

// ---- A-squared: MT[2i+1][w][v] = bf16( (A_i*A_i)[v][w] ), zero-padded -------
__global__ void k_sq(const float* __restrict__ A0, const float* __restrict__ A1,
                     const float* __restrict__ A2, u16* __restrict__ MT) {
  int idx = blockIdx.x * 256 + threadIdx.x;
  if (idx >= 3 * VP * VP) return;
  int i = idx / (VP * VP), r = idx % (VP * VP);
  int w = r / VP, v = r % VP;
  const float* A = (i == 0) ? A0 : ((i == 1) ? A1 : A2);
  float s = 0.f;
  if (w < VDIM && v < VDIM) {
#pragma unroll 4
    for (int u = 0; u < VDIM; ++u) s += A[v * VDIM + u] * A[u * VDIM + w];
  }
  MT[(size_t)(2 * i + 1) * (VP * VP) + r] = f2bf(s);
}

// ---------------- transpose x -> xT bf16 [nc][l=128][v=224] ----------------
__global__ __launch_bounds__(256) void k_xt(const float* __restrict__ x,
                                            u16* __restrict__ xT) {
  __shared__ float tile[64 * 130];  // [64 v][128 l] padded stride 130
  int nc = blockIdx.x;
  const float* xs = x + (size_t)nc * VL;
  u16* xd = xT + (size_t)nc * (128 * VP);
  int tid = threadIdx.x;
  for (int ch = 0; ch < 4; ++ch) {
    int v0 = ch * 64;
    __syncthreads();
#pragma unroll
    for (int j = 0; j < 8; ++j) {
      int idx = j * 256 + tid;
      int vr = idx >> 5, c4 = idx & 31;
      int v = v0 + vr;
      float4 val = make_float4(0.f, 0.f, 0.f, 0.f);
      if (v < VDIM) val = *(const float4*)(xs + (size_t)v * LDIM + c4 * 4);
      float* trow = &tile[vr * 130 + c4 * 4];
      *(float2*)(trow) = make_float2(val.x, val.y);
      *(float2*)(trow + 2) = make_float2(val.z, val.w);
    }
    __syncthreads();
    int l = tid >> 1, h = tid & 1;
    int vbase = v0 + h * 32;
    if (vbase < VP) {
      u32 wd[16];
#pragma unroll
      for (int j = 0; j < 16; ++j) {
        int v = vbase + 2 * j;
        float f0 = (v < VDIM) ? tile[(h * 32 + 2 * j) * 130 + l] : 0.f;
        float f1 = (v + 1 < VDIM) ? tile[(h * 32 + 2 * j + 1) * 130 + l] : 0.f;
        wd[j] = (u32)f2bf(f0) | ((u32)f2bf(f1) << 16);
      }
      uint4* dst = (uint4*)(xd + (size_t)l * VP + vbase);
#pragma unroll
      for (int t = 0; t < 4; ++t)
        dst[t] = make_uint4(wd[4 * t], wd[4 * t + 1], wd[4 * t + 2], wd[4 * t + 3]);
    }
  }
}

// ---- 6 independent GEMMs: z_j = M_j^T x per (n,c); M-chunked, A_s <=37KB ----
// NMT=5: grid=nc, rows 0..79.  NMT=4: grid=nc*2, rows 80..143 / 144..207.
// 4 waves (wn strips of 32 cols); b-frags (xT) hoisted across all matrices.
template <int NMT>
__global__ __launch_bounds__(256, 4) void k_gemm(const u16* __restrict__ xT,
                                                 const u16* __restrict__ MT,
                                                 u16* __restrict__ zbuf,
                                                 int j0, int jcount) {
  __shared__ __align__(16) u16 A_s[NMT * 16 * APITCH];
  int tid = threadIdx.x;
  int lane = tid & 63, wn = tid >> 6;
  int lane15 = lane & 15, lgrp = lane >> 4;
  int bid = blockIdx.x;
  int nc, rowbase;
  if (NMT == 5) { nc = bid; rowbase = 0; }
  else { nc = bid >> 1; rowbase = 80 + 64 * (bid & 1); }
  const u16* xg = xT + (size_t)nc * (128 * VP);
  int col0 = wn * 32 + lane15, col1 = col0 + 16;

  s16x8 bx0[7], bx1[7];
#pragma unroll
  for (int ks = 0; ks < 7; ++ks) {
    bx0[ks] = *(const s16x8*)(xg + (size_t)col0 * VP + ks * 32 + lgrp * 8);
    bx1[ks] = *(const s16x8*)(xg + (size_t)col1 * VP + ks * 32 + lgrp * 8);
  }

  for (int jj = 0; jj < jcount; ++jj) {
    const u16* Mg = MT + (size_t)(j0 + jj) * (VP * VP) + (size_t)rowbase * VP;
    // stage chunk: NMT*16 rows x 28 uint4
    for (int t = tid; t < NMT * 16 * 28; t += 256) {
      int r = t / 28, cq = t - r * 28;
      *(uint4*)((char*)A_s + SWZ(r, cq * 16)) = *(const uint4*)(Mg + r * VP + cq * 8);
    }
    __syncthreads();  // (B1) chunk staged

    f32x4 acc[NMT][2];
#pragma unroll
    for (int m = 0; m < NMT; ++m) {
      acc[m][0] = (f32x4){0.f, 0.f, 0.f, 0.f};
      acc[m][1] = (f32x4){0.f, 0.f, 0.f, 0.f};
    }
    for (int ks = 0; ks < 7; ++ks) {
      int colb = ks * 64 + lgrp * 16;
#pragma unroll
      for (int mt = 0; mt < NMT; ++mt) {
        s16x8 af = *(const s16x8*)((char*)A_s + SWZ(mt * 16 + lane15, colb));
        asm("v_mfma_f32_16x16x32_bf16 %0, %1, %2, %0"
            : "+v"(acc[mt][0]) : "v"(af), "v"(bx0[ks]));
        asm("v_mfma_f32_16x16x32_bf16 %0, %1, %2, %0"
            : "+v"(acc[mt][1]) : "v"(af), "v"(bx1[ks]));
      }
    }
    __syncthreads();  // (B2) LDS reads done; epilogue overlaps next staging

    u16* zg = zbuf + (size_t)jj * ((size_t)NC * VL) + (size_t)nc * VL;
#pragma unroll
    for (int mt = 0; mt < NMT; ++mt) {
#pragma unroll
      for (int nt = 0; nt < 2; ++nt) {
        f32x4 a = acc[mt][nt];
        int col = wn * 32 + nt * 16 + lane15;
        int wb = rowbase + mt * 16 + lgrp * 4;
        u16 u0 = f2bf(a.x), u1 = f2bf(a.y), u2 = f2bf(a.z), u3 = f2bf(a.w);
        if (wb + 0 < VDIM) zg[(wb + 0) * LDIM + col] = u0;
        if (wb + 1 < VDIM) zg[(wb + 1) * LDIM + col] = u1;
        if (wb + 2 < VDIM) zg[(wb + 2) * LDIM + col] = u2;
        if (wb + 3 < VDIM) zg[(wb + 3) * LDIM + col] = u3;
      }
    }
  }
}

// ---- MFMA channel mix v3: 8 waves, dbuf tile w/ XOR p-swizzle, 1 barrier/group
__global__ __launch_bounds__(512, 4) void k_mixm(const float* __restrict__ x,
                                                 const u16* __restrict__ zb,
                                                 const u16* __restrict__ Wb,
                                                 const float* __restrict__ bias,
                                                 float* __restrict__ out) {
  __shared__ __align__(16) u16 hT_s[128 * APITCH];  // 59,392 B
  __shared__ __align__(16) u16 tile[2][32 * 136];   // 2 x 8,704 B
  int tid = threadIdx.x;
  int bid = blockIdx.x;
  int n = bid / 207, pt = bid - n * 207;
  int p0 = pt * 128;
  int lane = tid & 63, wn = tid >> 6;   // 8 waves, 16-col strips
  int lane15 = lane & 15, lgrp = lane >> 4;

  s16x8 wa0[7], wa1[7];
#pragma unroll
  for (int ks = 0; ks < 7; ++ks) {
    wa0[ks] = *(const s16x8*)(Wb + lane15 * 224 + ks * 32 + lgrp * 8);
    wa1[ks] = *(const s16x8*)(Wb + (16 + lane15) * 224 + ks * 32 + lgrp * 8);
  }

  // stage x (group 0) into tile[0]: swizzled u32 stores
#pragma unroll
  for (int t = 0; t < 2; ++t) {
    int j = t * 512 + tid;
    int c = j >> 5, q = j & 31;
    float4 v = *(const float4*)(x + (size_t)(n * 32 + c) * VL + p0 + q * 4);
    int sc = 2 * ((c >> 3) & 3);
    u16* tp = tile[0] + c * 136;
    *(u32*)(tp + ((q * 4) ^ sc)) = (u32)f2bf(v.x) | ((u32)f2bf(v.y) << 16);
    *(u32*)(tp + ((q * 4 + 2) ^ sc)) = (u32)f2bf(v.z) | ((u32)f2bf(v.w) << 16);
  }
  __syncthreads();

  int cur = 0;
  int zc = tid >> 4, zq = tid & 15;     // z staging role
  for (int g7 = 0; g7 < 7; ++g7) {
    uint4 zv;
    if (g7 < 6)  // issue next group's global load early (T14)
      zv = *(const uint4*)(zb + ((size_t)(g7 << 10) + n * 32 + zc) * VL + p0 + zq * 8);
    // transpose tile[cur] -> hT_s k-range [g7*32, +32)
#pragma unroll
    for (int t = 0; t < 4; ++t) {
      int j = t * 512 + tid;
      int cp = j & 15, p = j >> 4;
      int sc = 2 * ((cp >> 2) & 3);     // == s(2cp) == s(2cp+1)
      const u16* tp = tile[cur];
      u32 w = (u32)tp[(2 * cp) * 136 + (p ^ sc)] |
              ((u32)tp[(2 * cp + 1) * 136 + (p ^ sc)] << 16);
      *(u32*)(hT_s + p * APITCH + g7 * 32 + 2 * cp) = w;
    }
    if (g7 < 6) {  // write staged group into the other buffer
      int sc = 2 * ((zc >> 3) & 3);
      u16* tp = tile[cur ^ 1] + zc * 136;
      u32 zd[4] = {zv.x, zv.y, zv.z, zv.w};
#pragma unroll
      for (int t = 0; t < 4; ++t)
        *(u32*)(tp + ((zq * 8 + 2 * t) ^ sc)) = zd[t];
    }
    __syncthreads();  // tile[cur^1] ready; tile[cur] reads drained
    cur ^= 1;
  }

  f32x4 acc[2];
  acc[0] = (f32x4){0.f, 0.f, 0.f, 0.f};
  acc[1] = (f32x4){0.f, 0.f, 0.f, 0.f};
  int colp = wn * 16 + lane15;
#pragma unroll
  for (int ks = 0; ks < 7; ++ks) {
    s16x8 bfrag = *(const s16x8*)(hT_s + colp * APITCH + ks * 32 + lgrp * 8);
    asm("v_mfma_f32_16x16x32_bf16 %0, %1, %2, %0"
        : "+v"(acc[0]) : "v"(wa0[ks]), "v"(bfrag));
    asm("v_mfma_f32_16x16x32_bf16 %0, %1, %2, %0"
        : "+v"(acc[1]) : "v"(wa1[ks]), "v"(bfrag));
  }

#pragma unroll
  for (int mt = 0; mt < 2; ++mt) {
#pragma unroll
    for (int j = 0; j < 4; ++j) {
      int o = mt * 16 + lgrp * 4 + j;
      out[(size_t)(n * 32 + o) * VL + p0 + colp] = acc[mt][j] + bias[o];
    }
  }
}

// ---------------- VALU channel mix (low-workspace fallback only) ----------------
template <int MODE, int NZ>
__global__ __launch_bounds__(256, 4) void k_mix(const float* __restrict__ x,
                                                const u16* __restrict__ zb,
                                                const float* __restrict__ WT,
                                                const float* __restrict__ bias,
                                                float* __restrict__ out, int wk0) {
  int t = blockIdx.x * 256 + threadIdx.x;
  int pp = t * 2;
  int n = pp / VL;
  int rem = pp - n * VL;
  float* op = out + (size_t)n * 32 * VL + rem;
  f32x4 a0[8], a1[8];

  if (MODE == 0) {
#pragma unroll
    for (int j = 0; j < 8; ++j) {
      f32x4 bv = *(const f32x4*)(bias + 4 * j);
      a0[j] = bv;
      a1[j] = bv;
    }
    const float* xp = x + (size_t)n * 32 * VL + rem;
#pragma unroll
    for (int c0 = 0; c0 < 32; c0 += 4) {
      float2 v[4];
#pragma unroll
      for (int q = 0; q < 4; ++q)
        v[q] = *(const float2*)(xp + (size_t)(c0 + q) * VL);
#pragma unroll
      for (int q = 0; q < 4; ++q) {
        const float* wv = WT + (c0 + q) * 32;
#pragma unroll
        for (int j = 0; j < 8; ++j) {
          f32x4 w4 = *(const f32x4*)(wv + 4 * j);
          a0[j] += w4 * v[q].x;
          a1[j] += w4 * v[q].y;
        }
      }
    }
  } else {
#pragma unroll
    for (int j = 0; j < 8; ++j) {
#pragma unroll
      for (int q = 0; q < 4; ++q) {
        float2 r = *(const float2*)(op + (size_t)(4 * j + q) * VL);
        a0[j][q] = r.x;
        a1[j][q] = r.y;
      }
    }
  }

#pragma unroll 1
  for (int g = 0; g < NZ; ++g) {
    const u16* zp = zb + ((size_t)g * NC + (size_t)n * 32) * VL + rem;
    const float* wg = WT + (wk0 + g * 32) * 32;
#pragma unroll
    for (int c0 = 0; c0 < 32; c0 += 4) {
      u32 zv[4];
#pragma unroll
      for (int q = 0; q < 4; ++q)
        zv[q] = *(const u32*)(zp + (size_t)(c0 + q) * VL);
#pragma unroll
      for (int q = 0; q < 4; ++q) {
        float f0 = bf2f((u16)(zv[q] & 0xFFFFu));
        float f1 = bf2f((u16)(zv[q] >> 16));
        const float* wv = wg + (c0 + q) * 32;
#pragma unroll
        for (int j = 0; j < 8; ++j) {
          f32x4 w4 = *(const f32x4*)(wv + 4 * j);
          a0[j] += w4 * f0;
          a1[j] += w4 * f1;
        }
      }
    }
  }

#pragma unroll
  for (int j = 0; j < 8; ++j) {
#pragma unroll
    for (int q = 0; q < 4; ++q) {
      float2 r;
      r.x = a0[j][q];
      r.y = a1[j][q];
      *(float2*)(op + (size_t)(4 * j + q) * VL) = r;
    }
  }
}

extern "C" void kernel_launch(void* const* d_in, const int* in_sizes, int n_in,
                              void* d_out, int out_size, void* d_ws, size_t ws_size,
                              hipStream_t stream) {
  const float* x = (const float*)d_in[0];
  const float* A0 = (const float*)d_in[1];
  const float* A1 = (const float*)d_in[2];
  const float* A2 = (const float*)d_in[3];
  const float* W = (const float*)d_in[4];
  const float* b = (const float*)d_in[5];
  float* out = (float*)d_out;

  const size_t xT_sz = (size_t)NC * 128 * VP * 2;  // 58,720,256
  const size_t MT_sz = (size_t)6 * VP * VP * 2;    // 602,112
  const size_t WT_sz = (size_t)VP * 32 * 4;        // 28,672
  const size_t Wb_sz = (size_t)VP * 32 * 2;        // 14,336
  const size_t slot_sz = (size_t)NC * VL * 2;      // 54,263,808

  char* wp = (char*)d_ws;
  u16* xT = (u16*)wp; wp += (xT_sz + 255) & ~(size_t)255;
  u16* MT = (u16*)wp; wp += (MT_sz + 255) & ~(size_t)255;
  float* WT = (float*)wp; wp += (WT_sz + 255) & ~(size_t)255;
  u16* Wb = (u16*)wp; wp += (Wb_sz + 255) & ~(size_t)255;
  u16* zbuf = (u16*)wp;
  size_t base = (size_t)(wp - (char*)d_ws);
  bool bigws = ws_size >= base + 6 * slot_sz;

  k_prep<<<644, 256, 0, stream>>>(A0, A1, A2, W, MT, WT, Wb);
  k_sq<<<588, 256, 0, stream>>>(A0, A1, A2, MT);
  k_xt<<<NC, 256, 0, stream>>>(x, xT);
  if (bigws) {
    k_gemm<5><<<NC, 256, 0, stream>>>(xT, MT, zbuf, 0, 6);
    k_gemm<4><<<2 * NC, 256, 0, stream>>>(xT, MT, zbuf, 0, 6);
    k_mixm<<<32 * 207, 512, 0, stream>>>(x, zbuf, Wb, b, out);
  } else {
    // low-workspace path: 2 z slots, accumulate per A-matrix (VALU k_mix)
    const int mixgrid = NPOINT / 512;
    k_mix<0, 0><<<mixgrid, 256, 0, stream>>>(x, nullptr, WT, b, out, 32);
    for (int i = 0; i < 3; ++i) {
      k_gemm<5><<<NC, 256, 0, stream>>>(xT, MT, zbuf, 2 * i, 2);
      k_gemm<4><<<2 * NC, 256, 0, stream>>>(xT, MT, zbuf, 2 * i, 2);
      k_mix<1, 2><<<mixgrid, 256, 0, stream>>>(nullptr, zbuf, WT, nullptr, out,
                                               (1 + 2 * i) * 32);
    }
  }
}

// Round 11
// 328.722 us; speedup vs baseline: 1.2379x; 1.2379x over previous
//
#include <hip/hip_runtime.h>

#define VDIM 207
#define LDIM 128
#define VP 224            // padded V (multiple of 16, covers K-steps 7*32)
#define VL (VDIM*LDIM)    // 26496
#define NC 1024           // B*C = 32*32
#define NPOINT (32*VL)    // B*V*L = 847872
#define APITCH 232        // LDS row pitch (u16): 464 B/row
#define SWZ(row, colb) ((row) * 464 + ((colb) ^ (((row) & 1) << 5)))

typedef unsigned short u16;
typedef unsigned int u32;
typedef __attribute__((ext_vector_type(4))) float f32x4;
typedef __attribute__((ext_vector_type(8))) short s16x8;

__device__ __forceinline__ u16 f2bf(float f) {
  u32 u = __float_as_uint(f);
  return (u16)((u + 0x7FFFu + ((u >> 16) & 1u)) >> 16);  // RNE
}
__device__ __forceinline__ float bf2f(u16 h) {
  return __uint_as_float(((u32)h) << 16);
}

// ---- prep: MT[2i] = bf16(A_i^T) zero-padded 224x224; WT (f32 fallback); Wb bf16
__global__ void k_prep(const float* __restrict__ A0, const float* __restrict__ A1,
                       const float* __restrict__ A2, const float* __restrict__ W,
                       u16* __restrict__ MT, float* __restrict__ WT,
                       u16* __restrict__ Wb) {
  int idx = blockIdx.x * 256 + threadIdx.x;
  if (idx < 3 * VP * VP) {
    int i = idx / (VP * VP);
    int r = idx % (VP * VP);
    int w = r / VP, v = r % VP;
    const float* A = (i == 0) ? A0 : ((i == 1) ? A1 : A2);
    float f = (w < VDIM && v < VDIM) ? A[v * VDIM + w] : 0.f;
    MT[(size_t)(2 * i) * (VP * VP) + r] = f2bf(f);
  } else {
    int j = idx - 3 * VP * VP;
    if (j < VP * 32) {
      int k = j >> 5, o = j & 31;
      WT[j] = W[o * 224 + k];
    } else if (j < 2 * VP * 32) {
      int j2 = j - VP * 32;
      Wb[j2] = f2bf(W[j2]);
    }
  }
}

// ---------------- transpose x -> xT bf16 [nc][l=128][v=224] ----------------
__global__ __launch_bounds__(256) void k_xt(const float* __restrict__ x,
                                            u16* __restrict__ xT) {
  __shared__ float tile[64 * 130];  // [64 v][128 l] padded stride 130
  int nc = blockIdx.x;
  const float* xs = x + (size_t)nc * VL;
  u16* xd = xT + (size_t)nc * (128 * VP);
  int tid = threadIdx.x;
  for (int ch = 0; ch < 4; ++ch) {
    int v0 = ch * 64;
    __syncthreads();
#pragma unroll
    for (int j = 0; j < 8; ++j) {
      int idx = j * 256 + tid;
      int vr = idx >> 5, c4 = idx & 31;
      int v = v0 + vr;
      float4 val = make_float4(0.f, 0.f, 0.f, 0.f);
      if (v < VDIM) val = *(const float4*)(xs + (size_t)v * LDIM + c4 * 4);
      float* trow = &tile[vr * 130 + c4 * 4];
      *(float2*)(trow) = make_float2(val.x, val.y);
      *(float2*)(trow + 2) = make_float2(val.z, val.w);
    }
    __syncthreads();
    int l = tid >> 1, h = tid & 1;
    int vbase = v0 + h * 32;
    if (vbase < VP) {
      u32 wd[16];
#pragma unroll
      for (int j = 0; j < 16; ++j) {
        int v = vbase + 2 * j;
        float f0 = (v < VDIM) ? tile[(h * 32 + 2 * j) * 130 + l] : 0.f;
        float f1 = (v + 1 < VDIM) ? tile[(h * 32 + 2 * j + 1) * 130 + l] : 0.f;
        wd[j] = (u32)f2bf(f0) | ((u32)f2bf(f1) << 16);
      }
      uint4* dst = (uint4*)(xd + (size_t)l * VP + vbase);
#pragma unroll
      for (int t = 0; t < 4; ++t)
        dst[t] = make_uint4(wd[4 * t], wd[4 * t + 1], wd[4 * t + 2], wd[4 * t + 3]);
    }
  }
}

// ---------------- fused double-hop v3: z1 = A^T x, z2 = A^T z1 (per (n,c)) ----
// R7-verified body; only edit: matrix i -> MT slot 2i.
__global__ __launch_bounds__(1024, 4) void k_hops(const u16* __restrict__ xT,
                                                  const u16* __restrict__ MT,
                                                  u16* __restrict__ zbuf,
                                                  int i0, int icount) {
  __shared__ __align__(16) u16 smem[208 * APITCH + 128 * APITCH];  // 155,904 B
  char* A_b = (char*)smem;
  char* z_b = (char*)(smem + 208 * APITCH);

  int tid = threadIdx.x;
  int lane = tid & 63, wid = tid >> 6;       // wid 0..15
  int lane15 = lane & 15, lgrp = lane >> 4;
  int wm = wid >> 2, wn = wid & 3;           // wave grid: 4 (M) x 4 (N)
  int NMT = (wm == 0) ? 4 : 3;               // m-tiles per wave-row (4+3+3+3=13)
  int mbase = (wm == 0) ? 0 : (16 + wm * 48);  // rows: 0 / 64 / 112 / 160
  int nc = blockIdx.x;
  const u16* xg = xT + (size_t)nc * (128 * VP);

  // zero z1T pad columns 208..223 once (hop1's K covers w in [0,224))
  if (tid < 256) {
    int l = tid >> 1, h = tid & 1;
    *(uint4*)(z_b + SWZ(l, 416 + 16 * h)) = make_uint4(0, 0, 0, 0);
  }

  int col0 = wn * 32 + lane15;        // n-tile 0 col (l)
  int col1 = col0 + 16;               // n-tile 1 col

  for (int ii = 0; ii < icount; ++ii) {
    int i = i0 + ii;
    const u16* Ag = MT + (size_t)(2 * i) * (VP * VP);
    // stage full A: 208 rows x 28 uint4 = 5824
    for (int j = tid; j < 5824; j += 1024) {
      int r = j / 28, cq = j - r * 28;
      *(uint4*)(A_b + SWZ(r, cq * 16)) = *(const uint4*)(Ag + r * VP + cq * 8);
    }
    __syncthreads();  // (B1) A ready; also covers z1T zero-fill / prior-i reuse

    for (int hop = 0; hop < 2; ++hop) {
      f32x4 acc[4][2];
#pragma unroll
      for (int m = 0; m < 4; ++m)
#pragma unroll
        for (int nt = 0; nt < 2; ++nt) acc[m][nt] = (f32x4){0.f, 0.f, 0.f, 0.f};

      for (int ks = 0; ks < 7; ++ks) {
        int colb = ks * 64 + lgrp * 16;   // byte offset of this K-slice
        s16x8 b0, b1;
        if (hop == 0) {
          b0 = *(const s16x8*)(xg + (size_t)col0 * VP + ks * 32 + lgrp * 8);
          b1 = *(const s16x8*)(xg + (size_t)col1 * VP + ks * 32 + lgrp * 8);
        } else {
          b0 = *(const s16x8*)(z_b + SWZ(col0, colb));
          b1 = *(const s16x8*)(z_b + SWZ(col1, colb));
        }
#pragma unroll
        for (int mt = 0; mt < 4; ++mt) {
          if (mt < NMT) {
            int row = mbase + mt * 16 + lane15;
            s16x8 afrag = *(const s16x8*)(A_b + SWZ(row, colb));
            asm("v_mfma_f32_16x16x32_bf16 %0, %1, %2, %0"
                : "+v"(acc[mt][0])
                : "v"(afrag), "v"(b0));
            asm("v_mfma_f32_16x16x32_bf16 %0, %1, %2, %0"
                : "+v"(acc[mt][1])
                : "v"(afrag), "v"(b1));
          }
        }
      }

      if (hop == 1) __syncthreads();  // (B3) hop1 A_s/z1T reads done before next i

      // epilogue: global z store (+ transposed LDS copy for hop1's B operand)
      int slot = 2 * ii + hop;
      u16* zg = zbuf + (size_t)slot * ((size_t)NC * VL) + (size_t)nc * VL;
#pragma unroll
      for (int mt = 0; mt < 4; ++mt) {
        if (mt < NMT) {
#pragma unroll
          for (int nt = 0; nt < 2; ++nt) {
            f32x4 a = acc[mt][nt];
            int col = wn * 32 + nt * 16 + lane15;     // l
            int wb = mbase + mt * 16 + lgrp * 4;      // w base (4 consecutive)
            u16 u0 = f2bf(a.x), u1 = f2bf(a.y), u2 = f2bf(a.z), u3 = f2bf(a.w);
            if (hop == 0) {
              uint2 pk = make_uint2((u32)u0 | ((u32)u1 << 16),
                                    (u32)u2 | ((u32)u3 << 16));
              *(uint2*)(z_b + SWZ(col, wb * 2)) = pk;
            }
            if (wb + 0 < VDIM) zg[(wb + 0) * LDIM + col] = u0;
            if (wb + 1 < VDIM) zg[(wb + 1) * LDIM + col] = u1;
            if (wb + 2 < VDIM) zg[(wb + 2) * LDIM + col] = u2;
            if (wb + 3 < VDIM) zg[(wb + 3) * LDIM + col] = u3;
          }
        }
      }
      if (hop == 0) __syncthreads();  // (B2) z1T fully written before hop1 reads
    }
  }
}

// ---- MFMA channel mix v3 (R8 VERBATIM, benched-passing): 8 waves, dbuf tile
// with XOR p-swizzle, in-loop 1-deep prefetch, 1 barrier/group.
__global__ __launch_bounds__(512, 4) void k_mixm(const float* __restrict__ x,
                                                 const u16* __restrict__ zb,
                                                 const u16* __restrict__ Wb,
                                                 const float* __restrict__ bias,
                                                 float* __restrict__ out) {
  __shared__ __align__(16) u16 hT_s[128 * APITCH];  // 59,392 B
  __shared__ __align__(16) u16 tile[2][32 * 136];   // 2 x 8,704 B
  int tid = threadIdx.x;
  int bid = blockIdx.x;
  int n = bid / 207, pt = bid - n * 207;
  int p0 = pt * 128;
  int lane = tid & 63, wn = tid >> 6;   // 8 waves, 16-col strips
  int lane15 = lane & 15, lgrp = lane >> 4;

  s16x8 wa0[7], wa1[7];
#pragma unroll
  for (int ks = 0; ks < 7; ++ks) {
    wa0[ks] = *(const s16x8*)(Wb + lane15 * 224 + ks * 32 + lgrp * 8);
    wa1[ks] = *(const s16x8*)(Wb + (16 + lane15) * 224 + ks * 32 + lgrp * 8);
  }

  // stage x (group 0) into tile[0]: swizzled u32 stores
#pragma unroll
  for (int t = 0; t < 2; ++t) {
    int j = t * 512 + tid;
    int c = j >> 5, q = j & 31;
    float4 v = *(const float4*)(x + (size_t)(n * 32 + c) * VL + p0 + q * 4);
    int sc = 2 * ((c >> 3) & 3);
    u16* tp = tile[0] + c * 136;
    *(u32*)(tp + ((q * 4) ^ sc)) = (u32)f2bf(v.x) | ((u32)f2bf(v.y) << 16);
    *(u32*)(tp + ((q * 4 + 2) ^ sc)) = (u32)f2bf(v.z) | ((u32)f2bf(v.w) << 16);
  }
  __syncthreads();

  int cur = 0;
  int zc = tid >> 4, zq = tid & 15;     // z staging role
  for (int g7 = 0; g7 < 7; ++g7) {
    uint4 zv;
    if (g7 < 6)  // issue next group's global load early (T14)
      zv = *(const uint4*)(zb + ((size_t)(g7 << 10) + n * 32 + zc) * VL + p0 + zq * 8);
    // transpose tile[cur] -> hT_s k-range [g7*32, +32)
#pragma unroll
    for (int t = 0; t < 4; ++t) {
      int j = t * 512 + tid;
      int cp = j & 15, p = j >> 4;
      int sc = 2 * ((cp >> 2) & 3);     // == s(2cp) == s(2cp+1)
      const u16* tp = tile[cur];
      u32 w = (u32)tp[(2 * cp) * 136 + (p ^ sc)] |
              ((u32)tp[(2 * cp + 1) * 136 + (p ^ sc)] << 16);
      *(u32*)(hT_s + p * APITCH + g7 * 32 + 2 * cp) = w;
    }
    if (g7 < 6) {  // write staged group into the other buffer
      int sc = 2 * ((zc >> 3) & 3);
      u16* tp = tile[cur ^ 1] + zc * 136;
      u32 zd[4] = {zv.x, zv.y, zv.z, zv.w};
#pragma unroll
      for (int t = 0; t < 4; ++t)
        *(u32*)(tp + ((zq * 8 + 2 * t) ^ sc)) = zd[t];
    }
    __syncthreads();  // tile[cur^1] ready; tile[cur] reads drained
    cur ^= 1;
  }

  f32x4 acc[2];
  acc[0] = (f32x4){0.f, 0.f, 0.f, 0.f};
  acc[1] = (f32x4){0.f, 0.f, 0.f, 0.f};
  int colp = wn * 16 + lane15;
#pragma unroll
  for (int ks = 0; ks < 7; ++ks) {
    s16x8 bfrag = *(const s16x8*)(hT_s + colp * APITCH + ks * 32 + lgrp * 8);
    asm("v_mfma_f32_16x16x32_bf16 %0, %1, %2, %0"
        : "+v"(acc[0]) : "v"(wa0[ks]), "v"(bfrag));
    asm("v_mfma_f32_16x16x32_bf16 %0, %1, %2, %0"
        : "+v"(acc[1]) : "v"(wa1[ks]), "v"(bfrag));
  }

#pragma unroll
  for (int mt = 0; mt < 2; ++mt) {
#pragma unroll
    for (int j = 0; j < 4; ++j) {
      int o = mt * 16 + lgrp * 4 + j;
      out[(size_t)(n * 32 + o) * VL + p0 + colp] = acc[mt][j] + bias[o];
    }
  }
}

// ---------------- VALU channel mix (low-workspace fallback only) ----------------
template <int MODE, int NZ>
__global__ __launch_bounds__(256, 4) void k_mix(const float* __restrict__ x,
                                                const u16* __restrict__ zb,
                                                const float* __restrict__ WT,
                                                const float* __restrict__ bias,
                                                float* __restrict__ out, int wk0) {
  int t = blockIdx.x * 256 + threadIdx.x;
  int pp = t * 2;
  int n = pp / VL;
  int rem = pp - n * VL;
  float* op = out + (size_t)n * 32 * VL + rem;
  f32x4 a0[8], a1[8];

  if (MODE == 0) {
#pragma unroll
    for (int j = 0; j < 8; ++j) {
      f32x4 bv = *(const f32x4*)(bias + 4 * j);
      a0[j] = bv;
      a1[j] = bv;
    }
    const float* xp = x + (size_t)n * 32 * VL + rem;
#pragma unroll
    for (int c0 = 0; c0 < 32; c0 += 4) {
      float2 v[4];
#pragma unroll
      for (int q = 0; q < 4; ++q)
        v[q] = *(const float2*)(xp + (size_t)(c0 + q) * VL);
#pragma unroll
      for (int q = 0; q < 4; ++q) {
        const float* wv = WT + (c0 + q) * 32;
#pragma unroll
        for (int j = 0; j < 8; ++j) {
          f32x4 w4 = *(const f32x4*)(wv + 4 * j);
          a0[j] += w4 * v[q].x;
          a1[j] += w4 * v[q].y;
        }
      }
    }
  } else {
#pragma unroll
    for (int j = 0; j < 8; ++j) {
#pragma unroll
      for (int q = 0; q < 4; ++q) {
        float2 r = *(const float2*)(op + (size_t)(4 * j + q) * VL);
        a0[j][q] = r.x;
        a1[j][q] = r.y;
      }
    }
  }

#pragma unroll 1
  for (int g = 0; g < NZ; ++g) {
    const u16* zp = zb + ((size_t)g * NC + (size_t)n * 32) * VL + rem;
    const float* wg = WT + (wk0 + g * 32) * 32;
#pragma unroll
    for (int c0 = 0; c0 < 32; c0 += 4) {
      u32 zv[4];
#pragma unroll
      for (int q = 0; q < 4; ++q)
        zv[q] = *(const u32*)(zp + (size_t)(c0 + q) * VL);
#pragma unroll
      for (int q = 0; q < 4; ++q) {
        float f0 = bf2f((u16)(zv[q] & 0xFFFFu));
        float f1 = bf2f((u16)(zv[q] >> 16));
        const float* wv = wg + (c0 + q) * 32;
#pragma unroll
        for (int j = 0; j < 8; ++j) {
          f32x4 w4 = *(const f32x4*)(wv + 4 * j);
          a0[j] += w4 * f0;
          a1[j] += w4 * f1;
        }
      }
    }
  }

#pragma unroll
  for (int j = 0; j < 8; ++j) {
#pragma unroll
    for (int q = 0; q < 4; ++q) {
      float2 r;
      r.x = a0[j][q];
      r.y = a1[j][q];
      *(float2*)(op + (size_t)(4 * j + q) * VL) = r;
    }
  }
}

extern "C" void kernel_launch(void* const* d_in, const int* in_sizes, int n_in,
                              void* d_out, int out_size, void* d_ws, size_t ws_size,
                              hipStream_t stream) {
  const float* x = (const float*)d_in[0];
  const float* A0 = (const float*)d_in[1];
  const float* A1 = (const float*)d_in[2];
  const float* A2 = (const float*)d_in[3];
  const float* W = (const float*)d_in[4];
  const float* b = (const float*)d_in[5];
  float* out = (float*)d_out;

  const size_t xT_sz = (size_t)NC * 128 * VP * 2;  // 58,720,256
  const size_t MT_sz = (size_t)6 * VP * VP * 2;    // 602,112
  const size_t WT_sz = (size_t)VP * 32 * 4;        // 28,672
  const size_t Wb_sz = (size_t)VP * 32 * 2;        // 14,336
  const size_t slot_sz = (size_t)NC * VL * 2;      // 54,263,808

  char* wp = (char*)d_ws;
  u16* xT = (u16*)wp; wp += (xT_sz + 255) & ~(size_t)255;
  u16* MT = (u16*)wp; wp += (MT_sz + 255) & ~(size_t)255;
  float* WT = (float*)wp; wp += (WT_sz + 255) & ~(size_t)255;
  u16* Wb = (u16*)wp; wp += (Wb_sz + 255) & ~(size_t)255;
  u16* zbuf = (u16*)wp;
  size_t base = (size_t)(wp - (char*)d_ws);
  bool bigws = ws_size >= base + 6 * slot_sz;

  k_prep<<<644, 256, 0, stream>>>(A0, A1, A2, W, MT, WT, Wb);
  k_xt<<<NC, 256, 0, stream>>>(x, xT);
  if (bigws) {
    k_hops<<<NC, 1024, 0, stream>>>(xT, MT, zbuf, 0, 3);
    k_mixm<<<32 * 207, 512, 0, stream>>>(x, zbuf, Wb, b, out);
  } else {
    // low-workspace path: 2 z slots, accumulate per A-matrix (VALU k_mix)
    const int mixgrid = NPOINT / 512;
    k_mix<0, 0><<<mixgrid, 256, 0, stream>>>(x, nullptr, WT, b, out, 32);
    for (int i = 0; i < 3; ++i) {
      k_hops<<<NC, 1024, 0, stream>>>(xT, MT, zbuf, i, 1);
      k_mix<1, 2><<<mixgrid, 256, 0, stream>>>(nullptr, zbuf, WT, nullptr, out,
                                               (1 + 2 * i) * 32);
    }
  }
}